// Round 2
// baseline (4470.610 us; speedup 1.0000x reference)
//
#include <hip/hip_runtime.h>

#define TT 512
#define VV 64
#define RING 32   // ch0 ring slots (4 KB each); lead band ~[17,31]

typedef _Float16 f16;
typedef f16 f16x8 __attribute__((ext_vector_type(8)));
typedef f16 f16x4 __attribute__((ext_vector_type(4)));
typedef float f32x4v __attribute__((ext_vector_type(4)));
typedef unsigned long long u64;
typedef unsigned u32;

#define MFMA(A_,B_,C_) __builtin_amdgcn_mfma_f32_16x16x32_f16((A_),(B_),(C_),0,0,0)
#define AT_LD32(p)   __hip_atomic_load((p), __ATOMIC_RELAXED, __HIP_MEMORY_SCOPE_AGENT)
#define AT_ST32(p,v) __hip_atomic_store((p),(v), __ATOMIC_RELAXED, __HIP_MEMORY_SCOPE_AGENT)
#define AT_LD64(p)   __hip_atomic_load((p), __ATOMIC_RELAXED, __HIP_MEMORY_SCOPE_AGENT)
#define AT_ST64(p,v) __hip_atomic_store((p),(v), __ATOMIC_RELAXED, __HIP_MEMORY_SCOPE_AGENT)

__device__ __forceinline__ void barrier_lds(){ asm volatile("s_waitcnt lgkmcnt(0)\n\ts_barrier" ::: "memory"); }
__device__ __forceinline__ void wait_vm0(){ asm volatile("s_waitcnt vmcnt(0)" ::: "memory"); }
__device__ __forceinline__ float4 ld4(const float* p){ return *(const float4*)p; }

__device__ __forceinline__ f16x8 ldA8(const float* p){
  f16x8 a;
  #pragma unroll
  for (int j = 0; j < 8; ++j) a[j] = (f16)p[j];
  return a;
}

// element offset (in f16 units) of (k=d0..d0+3, col=b) inside a B-frag buffer
// layout: [kt][lane'][j], lane' = ((d&31)>>3)*16 + b, j = d&7
__device__ __forceinline__ int fragOff16(int d0, int b){
  const int kt = d0 >> 5, qq = (d0 >> 3) & 3, j0 = d0 & 7;
  return (kt*64 + qq*16 + b)*8 + j0;
}

__device__ __forceinline__ void fragW_lds(f16x8* buf, int d0, int b, const float* h4){
  f16x4 v;
  #pragma unroll
  for (int e = 0; e < 4; ++e) v[e] = (f16)h4[e];
  *(f16x4*)((f16*)buf + fragOff16(d0, b)) = v;
}

__device__ __forceinline__ void pubFrag(char* slot, int d0, int b, const float* h4){
  union { f16x4 v; u64 u; } uu;
  #pragma unroll
  for (int e = 0; e < 4; ++e) uu.v[e] = (f16)h4[e];
  AT_ST64((u64*)(slot + fragOff16(d0, b)*2), uu.u);
}

__device__ __forceinline__ f16x8 impFrag(const char* slot, int kt, int lane){
  union { u64 u[2]; f16x8 v; } vv;
  const u64* p = (const u64*)(slot + (kt*64 + lane)*16);
  vv.u[0] = AT_LD64((u64*)p);
  vv.u[1] = AT_LD64((u64*)(p + 1));
  return vv.v;
}

__device__ __forceinline__ void spin_ge(u32* f, u32 val){
  if ((threadIdx.x & 63) == 0){
    u32 g = 0;
    while (AT_LD32(f) < val && ++g < (1u << 20)) {}
  }
  asm volatile("" ::: "memory");
}

__device__ __forceinline__ void gates_upd(const f32x4v* Ci, const f32x4v* Ch,
                                          const float* bR, const float* bZ,
                                          const float* bI, const float* bH,
                                          float* hp){
  #pragma unroll
  for (int e = 0; e < 4; ++e){
    float rr = 1.f/(1.f + __expf(-(Ci[0][e] + Ch[0][e] + bR[e])));
    float zz = 1.f/(1.f + __expf(-(Ci[1][e] + Ch[1][e] + bZ[e])));
    float nv = Ci[2][e] + bI[e] + rr*(Ch[2][e] + bH[e]);
    float nn = 1.f - 2.f/(1.f + __expf(2.f*nv));
    hp[e] = (1.f - zz)*nn + zz*hp[e];
  }
}

__global__ void k_init(u32* wsf){
  const int i = blockIdx.x*256 + threadIdx.x;
  if (i < 4096) AT_ST32(wsf + i, 0u);
}

// blocks 0..31: L1 producer (8 waves, 1 row-block each) -> ch0 (global ring)
// blocks 32..63: merged L2 (waves 0-3) + L3+head (waves 4-7); h2 handoff via LDS.
// ch0 protocol: flag = steps published, multiples of 8 (vm0-drained before store).
// consumer spin at s%8==7: flag >= min(s+17, TT); ACK = s+1 at s%8==7;
// producer gate at t%8==0, t>=32: ACK >= t-24. Ring 32 => no alias hazard
// (in-flight prefetch slot = ACK is outside producer's alias window, margin >= 1).
__launch_bounds__(512, 2)
__global__ void k_pipe(const float* __restrict__ x,   const float* __restrict__ dd,
                       const float* __restrict__ m1,
                       const float* __restrict__ h01, const float* __restrict__ h02,
                       const float* __restrict__ h03,
                       const float* __restrict__ Wih1, const float* __restrict__ Whh1,
                       const float* __restrict__ bih1, const float* __restrict__ bhh1,
                       const float* __restrict__ Wih2, const float* __restrict__ Whh2,
                       const float* __restrict__ bih2, const float* __restrict__ bhh2,
                       const float* __restrict__ Wih3, const float* __restrict__ Whh3,
                       const float* __restrict__ bih3, const float* __restrict__ bhh3,
                       const float* __restrict__ Wout, const float* __restrict__ bout,
                       const float* __restrict__ Wdx,  const float* __restrict__ bdx,
                       const float* __restrict__ Wdh,  const float* __restrict__ bdh,
                       float* __restrict__ y, u32* __restrict__ wsf, char* __restrict__ wsd)
{
  // producer: sA = h1 staging, sB(first 128) = x staging
  // consumer: sA = h2 decayed (L2's B), sB = h2 raw (L3's input),
  //           sC = h3 decayed (L3's B), sD = h3 raw (head input, 1-phase delayed)
  __shared__ f16x8 sA[2][256];
  __shared__ f16x8 sB[2][256];
  __shared__ f16x8 sC[2][256];
  __shared__ f16x8 sD[2][256];

  const int tid = threadIdx.x, wid = tid >> 6, lane = tid & 63;
  const int q = lane >> 4, r = lane & 15;
  const int blk = blockIdx.x;

  u32* const FL  = wsf;
  u32* const ACK = wsf + 1024;

  if (blk < 32){
    // ===================== L1 producer =====================
    const int grp = blk, b0 = grp << 4;
    u32* const flp  = FL  + grp*16;
    u32* const ackp = ACK + grp*16;
    char* const base = wsd + (size_t)grp*RING*4096;

    f16x8 Ai[3][2], Ah[3][4];
    #pragma unroll
    for (int g = 0; g < 3; ++g){
      const int mrow = (g*8 + wid)*16 + r;
      #pragma unroll
      for (int kt = 0; kt < 2; ++kt) Ai[g][kt] = ldA8(Wih1 + mrow*64 + kt*32 + q*8);
      #pragma unroll
      for (int kt = 0; kt < 4; ++kt) Ah[g][kt] = ldA8(Whh1 + mrow*128 + kt*32 + q*8);
    }
    const int dG = wid*16 + 4*q;
    float bR[4], bZ[4], bI[4], bH[4], hS[4], WdhL[4], bdhL[4];
    #pragma unroll
    for (int e = 0; e < 4; ++e){
      const int d = dG + e;
      bR[e] = bih1[d] + bhh1[d];
      bZ[e] = bih1[128+d] + bhh1[128+d];
      bI[e] = bih1[256+d];
      bH[e] = bhh1[256+d];
      WdhL[e] = Wdh[d]; bdhL[e] = bdh[d];
    }
    { float4 a = ld4(h01 + (size_t)(b0+r)*128 + dG); hS[0]=a.x; hS[1]=a.y; hS[2]=a.z; hS[3]=a.w; }
    float dhC = 0.f, dhN = dd[(size_t)(b0+r)*TT + 1];

    const int bx = (wid & 3)*4 + q, v0 = 4*r;
    float Wdx4[4] = {0,0,0,0}, bdx4[4] = {0,0,0,0};
    float4 xC = {0,0,0,0}, x0v = {0,0,0,0}, xN = {0,0,0,0}, mN = {0,0,0,0};
    float4 xP = {0,0,0,0}, mC = {0,0,0,0};
    float dxC = 0.f, dxN = 0.f;
    if (wid < 4){
      #pragma unroll
      for (int e = 0; e < 4; ++e){ Wdx4[e] = Wdx[v0+e]; bdx4[e] = bdx[v0+e]; }
      xC  = ld4(x + ((size_t)(b0+bx)*TT + 0)*VV + v0);
      x0v = xC;
      xN  = ld4(x  + ((size_t)(b0+bx)*TT + 1)*VV + v0);
      mN  = ld4(m1 + ((size_t)(b0+bx)*TT + 1)*VV + v0);
      dxN = dd[(size_t)(b0+bx)*TT + 1];
      xP = xC; mC = mN; dxC = dxN;
    }
    __syncthreads();

    for (int t = 0; t < TT; ++t){
      const int par = t & 1;
      if ((t & 7) == 0 && t >= 32) spin_ge(ackp, (u32)(t-24));
      if (wid < 4){
        float xi[4];
        if (t == 0){ xi[0]=xC.x; xi[1]=xC.y; xi[2]=xC.z; xi[3]=xC.w; }
        else {
          const float* xc = (const float*)&xC; const float* xp = (const float*)&xP;
          const float* x0e = (const float*)&x0v; const float* me = (const float*)&mC;
          #pragma unroll
          for (int e = 0; e < 4; ++e){
            float gx = __expf(-fmaxf(dxC*Wdx4[e] + bdx4[e], 0.f));
            xi[e] = (xp[e]*gx + (1.f-gx)*x0e[e])*(1.f-me[e]) + me[e]*xc[e];
          }
        }
        fragW_lds(&sB[par][0], v0, bx, xi);
      }
      if (t >= 1){
        #pragma unroll
        for (int e = 0; e < 4; ++e)
          hS[e] *= __expf(-fmaxf(dhC*WdhL[e] + bdhL[e], 0.f));
      }
      fragW_lds(&sA[par][0], dG, r, hS);
      barrier_lds();
      f16x8 bx1[2], bh4[4];
      #pragma unroll
      for (int kt = 0; kt < 2; ++kt) bx1[kt] = sB[par][kt*64 + lane];
      #pragma unroll
      for (int kt = 0; kt < 4; ++kt) bh4[kt] = sA[par][kt*64 + lane];
      f32x4v Ci[3], Ch[3];
      #pragma unroll
      for (int g = 0; g < 3; ++g){ Ci[g] = (f32x4v){0,0,0,0}; Ch[g] = (f32x4v){0,0,0,0}; }
      #pragma unroll
      for (int g = 0; g < 3; ++g){
        #pragma unroll
        for (int kt = 0; kt < 4; ++kt) Ch[g] = MFMA(Ah[g][kt], bh4[kt], Ch[g]);
        #pragma unroll
        for (int kt = 0; kt < 2; ++kt) Ci[g] = MFMA(Ai[g][kt], bx1[kt], Ci[g]);
      }
      gates_upd(Ci, Ch, bR, bZ, bI, bH, hS);
      pubFrag(base + (size_t)(t & (RING-1))*4096, dG, r, hS);
      if ((t & 7) == 7){
        wait_vm0();
        barrier_lds();
        if (tid == 0) AT_ST32(flp, (u32)(t+1));
      }
      dhC = dhN;
      const int tp = (t+2 < TT) ? (t+2) : (TT-1);
      dhN = dd[(size_t)(b0+r)*TT + tp];
      if (wid < 4){
        xP = xC; xC = xN; mC = mN; dxC = dxN;
        xN  = ld4(x  + ((size_t)(b0+bx)*TT + tp)*VV + v0);
        mN  = ld4(m1 + ((size_t)(b0+bx)*TT + tp)*VV + v0);
        dxN = dd[(size_t)(b0+bx)*TT + tp];
      }
    }
    return;
  }

  // ===================== merged L2 + L3/head =====================
  {
    const int grp = blk - 32, b0 = grp << 4;
    u32* const flp  = FL  + grp*16;
    u32* const ackp = ACK + grp*16;
    char* const base = wsd + (size_t)grp*RING*4096;
    const int half = wid >> 2, w = wid & 3;

    const float* Wihp = half ? Wih3 : Wih2;
    const float* Whhp = half ? Whh3 : Whh2;
    const float* bihX = half ? bih3 : bih2;
    const float* bhhX = half ? bhh3 : bhh2;
    const float* h0X  = half ? h03  : h02;

    f16x8 Ai[2][3][4], Ah[2][3][4];
    #pragma unroll
    for (int G = 0; G < 2; ++G)
      #pragma unroll
      for (int g = 0; g < 3; ++g){
        const int mrow = (g*8 + w + 4*G)*16 + r;
        #pragma unroll
        for (int kt = 0; kt < 4; ++kt){
          Ai[G][g][kt] = ldA8(Wihp + mrow*128 + kt*32 + q*8);
          Ah[G][g][kt] = ldA8(Whhp + mrow*128 + kt*32 + q*8);
        }
      }
    float bR[2][4], bZ[2][4], bI[2][4], bH[2][4], hS[2][4], WdhL[2][4], bdhL[2][4];
    #pragma unroll
    for (int G = 0; G < 2; ++G){
      const int dG = (w + 4*G)*16 + 4*q;
      #pragma unroll
      for (int e = 0; e < 4; ++e){
        const int d = dG + e;
        bR[G][e] = bihX[d] + bhhX[d];
        bZ[G][e] = bihX[128+d] + bhhX[128+d];
        bI[G][e] = bihX[256+d];
        bH[G][e] = bhhX[256+d];
        WdhL[G][e] = Wdh[d]; bdhL[G][e] = bdh[d];
      }
      float4 a = ld4(h0X + (size_t)(b0+r)*128 + dG);
      hS[G][0]=a.x; hS[G][1]=a.y; hS[G][2]=a.z; hS[G][3]=a.w;
    }
    // head weights: only wave 4 computes/stores the head
    f16x8 aO[4]; float bo4[4] = {0,0,0,0};
    if (wid == 4){
      #pragma unroll
      for (int kt = 0; kt < 4; ++kt){
        f16x8 a;
        #pragma unroll
        for (int j = 0; j < 8; ++j)
          a[j] = (r < 4) ? (f16)Wout[r*128 + kt*32 + q*8 + j] : (f16)0.f;
        aO[kt] = a;
      }
      #pragma unroll
      for (int e = 0; e < 4; ++e) bo4[e] = bout[e];
    }
    __syncthreads();

    f16x8 bi[4];
    if (half == 0){
      spin_ge(flp, 16u);                       // covers slot 0 + window-0 prefetches
      #pragma unroll
      for (int kt = 0; kt < 4; ++kt) bi[kt] = impFrag(base, kt, lane);   // slot 0
    }
    float dhC = 0.f, dhN = dd[(size_t)(b0+r)*TT + (half ? 0 : 1)];

    for (int s = 0; s < TT+2; ++s){
      const int par = s & 1;
      if (half == 0){
        // stage RAW h2(s-1) for L3 (valid/needed for s in [1,TT])
        if (s <= TT){
          #pragma unroll
          for (int G = 0; G < 2; ++G){
            const int dG = (w + 4*G)*16 + 4*q;
            fragW_lds(&sB[par][0], dG, r, hS[G]);
          }
        }
        if (s >= 1 && s < TT){
          #pragma unroll
          for (int G = 0; G < 2; ++G)
            #pragma unroll
            for (int e = 0; e < 4; ++e)
              hS[G][e] *= __expf(-fmaxf(dhC*WdhL[G][e] + bdhL[G][e], 0.f));
        }
        if (s < TT){
          #pragma unroll
          for (int G = 0; G < 2; ++G){
            const int dG = (w + 4*G)*16 + 4*q;
            fragW_lds(&sA[par][0], dG, r, hS[G]);   // decayed: own Whh2 B-operand
          }
        }
      } else {
        // stage RAW h3(s-2) for head (head consumes at this same phase)
        #pragma unroll
        for (int G = 0; G < 2; ++G){
          const int dG = (w + 4*G)*16 + 4*q;
          fragW_lds(&sD[par][0], dG, r, hS[G]);
        }
        if (s >= 2 && s <= TT){
          #pragma unroll
          for (int G = 0; G < 2; ++G)
            #pragma unroll
            for (int e = 0; e < 4; ++e)
              hS[G][e] *= __expf(-fmaxf(dhC*WdhL[G][e] + bdhL[G][e], 0.f));
        }
        if (s >= 1 && s <= TT){
          #pragma unroll
          for (int G = 0; G < 2; ++G){
            const int dG = (w + 4*G)*16 + 4*q;
            fragW_lds(&sC[par][0], dG, r, hS[G]);   // decayed: own Whh3 B-operand
          }
        }
      }
      barrier_lds();
      if (half == 0){
        if (s < TT){
          f16x8 bh4[4];
          #pragma unroll
          for (int kt = 0; kt < 4; ++kt) bh4[kt] = sA[par][kt*64 + lane];
          f32x4v Ci[2][3], Ch[2][3];
          #pragma unroll
          for (int G = 0; G < 2; ++G)
            #pragma unroll
            for (int g = 0; g < 3; ++g){ Ci[G][g] = (f32x4v){0,0,0,0}; Ch[G][g] = (f32x4v){0,0,0,0}; }
          #pragma unroll
          for (int G = 0; G < 2; ++G)
            #pragma unroll
            for (int g = 0; g < 3; ++g){
              #pragma unroll
              for (int kt = 0; kt < 4; ++kt) Ch[G][g] = MFMA(Ah[G][g][kt], bh4[kt], Ch[G][g]);
              #pragma unroll
              for (int kt = 0; kt < 4; ++kt) Ci[G][g] = MFMA(Ai[G][g][kt], bi[kt], Ci[G][g]);
            }
          // prefetch next step's h1 frags right after bi's last use (full-phase cover)
          if (s + 1 < TT){
            const char* sIn = base + (size_t)((s+1) & (RING-1))*4096;
            #pragma unroll
            for (int kt = 0; kt < 4; ++kt) bi[kt] = impFrag(sIn, kt, lane);
          }
          #pragma unroll
          for (int G = 0; G < 2; ++G)
            gates_upd(&Ci[G][0], &Ch[G][0], bR[G], bZ[G], bI[G], bH[G], hS[G]);
          if ((s & 7) == 7){
            if (tid == 0) AT_ST32(ackp, (u32)(s+1));
            spin_ge(flp, (u32)(s+17 <= TT ? s+17 : TT));
          }
        }
      } else {
        if (s >= 1 && s <= TT){
          f16x8 bh4[4], bi3[4];
          #pragma unroll
          for (int kt = 0; kt < 4; ++kt) bh4[kt] = sC[par][kt*64 + lane];
          #pragma unroll
          for (int kt = 0; kt < 4; ++kt) bi3[kt] = sB[par][kt*64 + lane];
          f32x4v Ci[2][3], Ch[2][3];
          #pragma unroll
          for (int G = 0; G < 2; ++G)
            #pragma unroll
            for (int g = 0; g < 3; ++g){ Ci[G][g] = (f32x4v){0,0,0,0}; Ch[G][g] = (f32x4v){0,0,0,0}; }
          #pragma unroll
          for (int G = 0; G < 2; ++G)
            #pragma unroll
            for (int g = 0; g < 3; ++g){
              #pragma unroll
              for (int kt = 0; kt < 4; ++kt) Ch[G][g] = MFMA(Ah[G][g][kt], bh4[kt], Ch[G][g]);
              #pragma unroll
              for (int kt = 0; kt < 4; ++kt) Ci[G][g] = MFMA(Ai[G][g][kt], bi3[kt], Ci[G][g]);
            }
          #pragma unroll
          for (int G = 0; G < 2; ++G)
            gates_upd(&Ci[G][0], &Ch[G][0], bR[G], bZ[G], bI[G], bH[G], hS[G]);
        }
        if (s >= 2 && wid == 4){
          f32x4v cl = {0.f,0.f,0.f,0.f};
          #pragma unroll
          for (int kt = 0; kt < 4; ++kt) cl = MFMA(aO[kt], sD[par][kt*64 + lane], cl);
          if (lane < 16){
            float l0 = cl[0]+bo4[0], l1 = cl[1]+bo4[1], l2 = cl[2]+bo4[2], l3 = cl[3]+bo4[3];
            float mx = fmaxf(fmaxf(l0,l1), fmaxf(l2,l3));
            float e0 = __expf(l0-mx), e1 = __expf(l1-mx), e2 = __expf(l2-mx), e3 = __expf(l3-mx);
            float inv = 1.f/(e0+e1+e2+e3);
            float4 o; o.x = e0*inv; o.y = e1*inv; o.z = e2*inv; o.w = e3*inv;
            *(float4*)(y + ((size_t)(b0+lane)*TT + (s-2))*4) = o;
          }
        }
      }
      dhC = dhN;
      const int tn = s + (half ? 1 : 2);
      const int tp = (tn < TT) ? tn : (TT-1);
      dhN = dd[(size_t)(b0+r)*TT + tp];
    }
  }
}

extern "C" void kernel_launch(void* const* d_in, const int* in_sizes, int n_in,
                              void* d_out, int out_size, void* d_ws, size_t ws_size,
                              hipStream_t stream) {
  (void)in_sizes; (void)n_in; (void)out_size; (void)ws_size;
  u32*  wsf = (u32*)d_ws;
  char* wsd = (char*)d_ws + 16384;
  k_init<<<dim3(16), dim3(256), 0, stream>>>(wsf);
  k_pipe<<<dim3(64), dim3(512), 0, stream>>>(
      (const float*)d_in[0],  (const float*)d_in[1],  (const float*)d_in[2],
      (const float*)d_in[3],  (const float*)d_in[4],  (const float*)d_in[5],
      (const float*)d_in[6],  (const float*)d_in[7],  (const float*)d_in[8],  (const float*)d_in[9],
      (const float*)d_in[10], (const float*)d_in[11], (const float*)d_in[12], (const float*)d_in[13],
      (const float*)d_in[14], (const float*)d_in[15], (const float*)d_in[16], (const float*)d_in[17],
      (const float*)d_in[18], (const float*)d_in[19],
      (const float*)d_in[20], (const float*)d_in[21],
      (const float*)d_in[22], (const float*)d_in[23],
      (float*)d_out, wsf, wsd);
}

// Round 3
// 1972.716 us; speedup vs baseline: 2.2662x; 2.2662x over previous
//
#include <hip/hip_runtime.h>

#define TT 512
#define VV 64
#define RING 16   // per channel; window 8, producer gate ACK >= t-8 (alias-safe by 1 slot)

typedef _Float16 f16;
typedef f16 f16x8 __attribute__((ext_vector_type(8)));
typedef f16 f16x4 __attribute__((ext_vector_type(4)));
typedef float f32x4v __attribute__((ext_vector_type(4)));
typedef unsigned long long u64;
typedef unsigned u32;

#define MFMA(A_,B_,C_) __builtin_amdgcn_mfma_f32_16x16x32_f16((A_),(B_),(C_),0,0,0)
#define AT_LD32(p)   __hip_atomic_load((p), __ATOMIC_RELAXED, __HIP_MEMORY_SCOPE_AGENT)
#define AT_ST32(p,v) __hip_atomic_store((p),(v), __ATOMIC_RELAXED, __HIP_MEMORY_SCOPE_AGENT)
#define AT_LD64(p)   __hip_atomic_load((p), __ATOMIC_RELAXED, __HIP_MEMORY_SCOPE_AGENT)
#define AT_ST64(p,v) __hip_atomic_store((p),(v), __ATOMIC_RELAXED, __HIP_MEMORY_SCOPE_AGENT)

__device__ __forceinline__ void barrier_lds(){ asm volatile("s_waitcnt lgkmcnt(0)\n\ts_barrier" ::: "memory"); }
__device__ __forceinline__ void wait_vm0(){ asm volatile("s_waitcnt vmcnt(0)" ::: "memory"); }
__device__ __forceinline__ float4 ld4(const float* p){ return *(const float4*)p; }

__device__ __forceinline__ f16x8 ldA8(const float* p){
  f16x8 a;
  #pragma unroll
  for (int j = 0; j < 8; ++j) a[j] = (f16)p[j];
  return a;
}

// element offset (in f16 units) of (k=d0..d0+3, col=b) inside a B-frag buffer
// layout: [kt][lane'][j], lane' = ((d&31)>>3)*16 + b, j = d&7
__device__ __forceinline__ int fragOff16(int d0, int b){
  const int kt = d0 >> 5, qq = (d0 >> 3) & 3, j0 = d0 & 7;
  return (kt*64 + qq*16 + b)*8 + j0;
}

__device__ __forceinline__ void fragW_lds(f16x8* buf, int d0, int b, const float* h4){
  f16x4 v;
  #pragma unroll
  for (int e = 0; e < 4; ++e) v[e] = (f16)h4[e];
  *(f16x4*)((f16*)buf + fragOff16(d0, b)) = v;
}

__device__ __forceinline__ void pubFrag(char* slot, int d0, int b, const float* h4){
  union { f16x4 v; u64 u; } uu;
  #pragma unroll
  for (int e = 0; e < 4; ++e) uu.v[e] = (f16)h4[e];
  AT_ST64((u64*)(slot + fragOff16(d0, b)*2), uu.u);
}

__device__ __forceinline__ f16x8 impFrag(const char* slot, int kt, int lane){
  union { u64 u[2]; f16x8 v; } vv;
  const u64* p = (const u64*)(slot + (kt*64 + lane)*16);
  vv.u[0] = AT_LD64((u64*)p);
  vv.u[1] = AT_LD64((u64*)(p + 1));
  return vv.v;
}

__device__ __forceinline__ void spin_ge(u32* f, u32 val){
  if ((threadIdx.x & 63) == 0){
    u32 g = 0;
    while (AT_LD32(f) < val && ++g < (1u << 20)) {}
  }
  asm volatile("" ::: "memory");
}

__device__ __forceinline__ void gates_upd(const f32x4v* Ci, const f32x4v* Ch,
                                          const float* bR, const float* bZ,
                                          const float* bI, const float* bH,
                                          float* hp){
  #pragma unroll
  for (int e = 0; e < 4; ++e){
    float rr = 1.f/(1.f + __expf(-(Ci[0][e] + Ch[0][e] + bR[e])));
    float zz = 1.f/(1.f + __expf(-(Ci[1][e] + Ch[1][e] + bZ[e])));
    float nv = Ci[2][e] + bI[e] + rr*(Ch[2][e] + bH[e]);
    float nn = 1.f - 2.f/(1.f + __expf(2.f*nv));
    hp[e] = (1.f - zz)*nn + zz*hp[e];
  }
}

__global__ void k_init(u32* wsf){
  const int i = blockIdx.x*256 + threadIdx.x;
  if (i < 4096) AT_ST32(wsf + i, 0u);
}

// blocks 0..31: L1 (x-path -> ch0); 32..63: L2 (ch0 -> ch1); 64..95: L3+head (ch1 -> y).
// All blocks: 512 threads = 8 waves (2 waves/SIMD for TLP), each wave owns ONE 16-row
// tile of H (G=1) so weights stay ~96 VGPR/wave -> no spills at the 256 cap.
// Protocol per channel (verified in R2): flag = steps published, stored every 8 steps
// after vm0 drain + block barrier; consumer ACK = s+1 every 8 steps; producer gate at
// window start (t%8==0, t>=16): ACK >= t-8 (max written step = ACK+15; alias needs
// ACK+16 -> safe, incl. consumer's in-flight prefetch of slot ACK). Consumer window
// spin: flag >= min(s+17, TT). Initial consumer spin: flag >= 16.
__launch_bounds__(512)
__global__ void k_pipe(const float* __restrict__ x,   const float* __restrict__ dd,
                       const float* __restrict__ m1,
                       const float* __restrict__ h01, const float* __restrict__ h02,
                       const float* __restrict__ h03,
                       const float* __restrict__ Wih1, const float* __restrict__ Whh1,
                       const float* __restrict__ bih1, const float* __restrict__ bhh1,
                       const float* __restrict__ Wih2, const float* __restrict__ Whh2,
                       const float* __restrict__ bih2, const float* __restrict__ bhh2,
                       const float* __restrict__ Wih3, const float* __restrict__ Whh3,
                       const float* __restrict__ bih3, const float* __restrict__ bhh3,
                       const float* __restrict__ Wout, const float* __restrict__ bout,
                       const float* __restrict__ Wdx,  const float* __restrict__ bdx,
                       const float* __restrict__ Wdh,  const float* __restrict__ bdh,
                       float* __restrict__ y, u32* __restrict__ wsf, char* __restrict__ wsd)
{
  __shared__ f16x8 sA[2][256];   // h staging (producer h1, L2 decayed-h2)
  __shared__ f16x8 sB[2][256];   // producer: x staging (first 128 used)
  __shared__ f16x8 sC[2][256];   // L3: decayed-h3 staging
  __shared__ f16x8 sD[2][256];   // L3: raw-h3 staging for delayed head

  const int tid = threadIdx.x, wid = tid >> 6, lane = tid & 63;
  const int q = lane >> 4, r = lane & 15;
  const int blk = blockIdx.x, role = blk >> 5, grp = blk & 31, b0 = grp << 4;

  u32* const FL  = wsf;
  u32* const ACK = wsf + 1024;
  u32* const fl0 = FL  + grp*16;
  u32* const ak0 = ACK + grp*16;
  u32* const fl1 = FL  + (32+grp)*16;
  u32* const ak1 = ACK + (32+grp)*16;
  char* const ring0 = wsd + (size_t)grp*RING*4096;
  char* const ring1 = wsd + (size_t)(32+grp)*RING*4096;

  const int dG = wid*16 + 4*q;

  const float* bihX = (role == 0) ? bih1 : (role == 1) ? bih2 : bih3;
  const float* bhhX = (role == 0) ? bhh1 : (role == 1) ? bhh2 : bhh3;
  const float* h0X  = (role == 0) ? h01  : (role == 1) ? h02  : h03;

  float bR[4], bZ[4], bI[4], bH[4], hS[4], WdhL[4], bdhL[4];
  #pragma unroll
  for (int e = 0; e < 4; ++e){
    const int d = dG + e;
    bR[e] = bihX[d] + bhhX[d];
    bZ[e] = bihX[128+d] + bhhX[128+d];
    bI[e] = bihX[256+d];
    bH[e] = bhhX[256+d];
    WdhL[e] = Wdh[d]; bdhL[e] = bdh[d];
  }
  { float4 a = ld4(h0X + (size_t)(b0+r)*128 + dG); hS[0]=a.x; hS[1]=a.y; hS[2]=a.z; hS[3]=a.w; }
  float dhC = 0.f, dhN = dd[(size_t)(b0+r)*TT + 1];

  // ===================== role 0: L1 producer =====================
  if (role == 0){
    f16x8 Ai[3][2], Ah[3][4];
    #pragma unroll
    for (int g = 0; g < 3; ++g){
      const int mrow = (g*8 + wid)*16 + r;
      #pragma unroll
      for (int kt = 0; kt < 2; ++kt) Ai[g][kt] = ldA8(Wih1 + mrow*64 + kt*32 + q*8);
      #pragma unroll
      for (int kt = 0; kt < 4; ++kt) Ah[g][kt] = ldA8(Whh1 + mrow*128 + kt*32 + q*8);
    }
    const int bx = (wid & 3)*4 + q, v0 = 4*r;
    float Wdx4[4] = {0,0,0,0}, bdx4[4] = {0,0,0,0};
    float4 xC = {0,0,0,0}, x0v = {0,0,0,0}, xN = {0,0,0,0}, mN = {0,0,0,0};
    float4 xP = {0,0,0,0}, mC = {0,0,0,0};
    float dxC = 0.f, dxN = 0.f;
    if (wid < 4){
      #pragma unroll
      for (int e = 0; e < 4; ++e){ Wdx4[e] = Wdx[v0+e]; bdx4[e] = bdx[v0+e]; }
      xC  = ld4(x + ((size_t)(b0+bx)*TT + 0)*VV + v0);
      x0v = xC;
      xN  = ld4(x  + ((size_t)(b0+bx)*TT + 1)*VV + v0);
      mN  = ld4(m1 + ((size_t)(b0+bx)*TT + 1)*VV + v0);
      dxN = dd[(size_t)(b0+bx)*TT + 1];
      xP = xC; mC = mN; dxC = dxN;
    }
    __syncthreads();

    for (int t = 0; t < TT; ++t){
      const int par = t & 1;
      if ((t & 7) == 0 && t >= 16) spin_ge(ak0, (u32)(t-8));
      if (wid < 4){
        float xi[4];
        if (t == 0){ xi[0]=xC.x; xi[1]=xC.y; xi[2]=xC.z; xi[3]=xC.w; }
        else {
          const float* xc = (const float*)&xC; const float* xp = (const float*)&xP;
          const float* x0e = (const float*)&x0v; const float* me = (const float*)&mC;
          #pragma unroll
          for (int e = 0; e < 4; ++e){
            float gx = __expf(-fmaxf(dxC*Wdx4[e] + bdx4[e], 0.f));
            xi[e] = (xp[e]*gx + (1.f-gx)*x0e[e])*(1.f-me[e]) + me[e]*xc[e];
          }
        }
        fragW_lds(&sB[par][0], v0, bx, xi);
      }
      if (t >= 1){
        #pragma unroll
        for (int e = 0; e < 4; ++e)
          hS[e] *= __expf(-fmaxf(dhC*WdhL[e] + bdhL[e], 0.f));
      }
      fragW_lds(&sA[par][0], dG, r, hS);
      barrier_lds();
      f16x8 bx1[2], bh4[4];
      #pragma unroll
      for (int kt = 0; kt < 2; ++kt) bx1[kt] = sB[par][kt*64 + lane];
      #pragma unroll
      for (int kt = 0; kt < 4; ++kt) bh4[kt] = sA[par][kt*64 + lane];
      f32x4v Ci[3], Ch[3];
      #pragma unroll
      for (int g = 0; g < 3; ++g){ Ci[g] = (f32x4v){0,0,0,0}; Ch[g] = (f32x4v){0,0,0,0}; }
      #pragma unroll
      for (int g = 0; g < 3; ++g){
        #pragma unroll
        for (int kt = 0; kt < 4; ++kt) Ch[g] = MFMA(Ah[g][kt], bh4[kt], Ch[g]);
        #pragma unroll
        for (int kt = 0; kt < 2; ++kt) Ci[g] = MFMA(Ai[g][kt], bx1[kt], Ci[g]);
      }
      gates_upd(Ci, Ch, bR, bZ, bI, bH, hS);
      pubFrag(ring0 + (size_t)(t & (RING-1))*4096, dG, r, hS);
      if ((t & 7) == 7){
        wait_vm0();
        barrier_lds();
        if (tid == 0) AT_ST32(fl0, (u32)(t+1));
      }
      dhC = dhN;
      const int tp = (t+2 < TT) ? (t+2) : (TT-1);
      dhN = dd[(size_t)(b0+r)*TT + tp];
      if (wid < 4){
        xP = xC; xC = xN; mC = mN; dxC = dxN;
        xN  = ld4(x  + ((size_t)(b0+bx)*TT + tp)*VV + v0);
        mN  = ld4(m1 + ((size_t)(b0+bx)*TT + tp)*VV + v0);
        dxN = dd[(size_t)(b0+bx)*TT + tp];
      }
    }
    return;
  }

  // ===================== role 1: L2 (ch0 -> ch1) =====================
  if (role == 1){
    f16x8 Ai[3][4], Ah[3][4];
    #pragma unroll
    for (int g = 0; g < 3; ++g){
      const int mrow = (g*8 + wid)*16 + r;
      #pragma unroll
      for (int kt = 0; kt < 4; ++kt){
        Ai[g][kt] = ldA8(Wih2 + mrow*128 + kt*32 + q*8);
        Ah[g][kt] = ldA8(Whh2 + mrow*128 + kt*32 + q*8);
      }
    }
    __syncthreads();

    spin_ge(fl0, 16u);
    f16x8 bi[4];
    #pragma unroll
    for (int kt = 0; kt < 4; ++kt) bi[kt] = impFrag(ring0, kt, lane);

    for (int s = 0; s < TT; ++s){
      const int par = s & 1;
      if ((s & 7) == 0 && s >= 16) spin_ge(ak1, (u32)(s-8));
      if (s >= 1){
        #pragma unroll
        for (int e = 0; e < 4; ++e)
          hS[e] *= __expf(-fmaxf(dhC*WdhL[e] + bdhL[e], 0.f));
      }
      fragW_lds(&sA[par][0], dG, r, hS);
      barrier_lds();
      f16x8 bh4[4];
      #pragma unroll
      for (int kt = 0; kt < 4; ++kt) bh4[kt] = sA[par][kt*64 + lane];
      f32x4v Ci[3], Ch[3];
      #pragma unroll
      for (int g = 0; g < 3; ++g){ Ci[g] = (f32x4v){0,0,0,0}; Ch[g] = (f32x4v){0,0,0,0}; }
      #pragma unroll
      for (int g = 0; g < 3; ++g){
        #pragma unroll
        for (int kt = 0; kt < 4; ++kt) Ch[g] = MFMA(Ah[g][kt], bh4[kt], Ch[g]);
        #pragma unroll
        for (int kt = 0; kt < 4; ++kt) Ci[g] = MFMA(Ai[g][kt], bi[kt], Ci[g]);
      }
      if (s + 1 < TT){
        const char* sIn = ring0 + (size_t)((s+1) & (RING-1))*4096;
        #pragma unroll
        for (int kt = 0; kt < 4; ++kt) bi[kt] = impFrag(sIn, kt, lane);
      }
      gates_upd(Ci, Ch, bR, bZ, bI, bH, hS);
      pubFrag(ring1 + (size_t)(s & (RING-1))*4096, dG, r, hS);
      if ((s & 7) == 7){
        wait_vm0();
        barrier_lds();
        if (tid == 0){ AT_ST32(fl1, (u32)(s+1)); AT_ST32(ak0, (u32)(s+1)); }
        spin_ge(fl0, (u32)(s+17 <= TT ? s+17 : TT));
      }
      dhC = dhN;
      const int tp = (s+2 < TT) ? (s+2) : (TT-1);
      dhN = dd[(size_t)(b0+r)*TT + tp];
    }
    return;
  }

  // ===================== role 2: L3 + head (ch1 -> y) =====================
  {
    f16x8 Ai[3][4], Ah[3][4];
    #pragma unroll
    for (int g = 0; g < 3; ++g){
      const int mrow = (g*8 + wid)*16 + r;
      #pragma unroll
      for (int kt = 0; kt < 4; ++kt){
        Ai[g][kt] = ldA8(Wih3 + mrow*128 + kt*32 + q*8);
        Ah[g][kt] = ldA8(Whh3 + mrow*128 + kt*32 + q*8);
      }
    }
    f16x8 aO[4]; float bo4[4] = {0,0,0,0};
    if (wid == 4){
      #pragma unroll
      for (int kt = 0; kt < 4; ++kt){
        f16x8 a;
        #pragma unroll
        for (int j = 0; j < 8; ++j)
          a[j] = (r < 4) ? (f16)Wout[r*128 + kt*32 + q*8 + j] : (f16)0.f;
        aO[kt] = a;
      }
      #pragma unroll
      for (int e = 0; e < 4; ++e) bo4[e] = bout[e];
    }
    __syncthreads();

    spin_ge(fl1, 16u);
    f16x8 bi[4];
    #pragma unroll
    for (int kt = 0; kt < 4; ++kt) bi[kt] = impFrag(ring1, kt, lane);

    // s in [0, TT]: GRU step s for s<TT; head(h3(s-1)) -> y(s-1) for s>=1 (delayed head, one barrier)
    for (int s = 0; s <= TT; ++s){
      const int par = s & 1;
      fragW_lds(&sD[par][0], dG, r, hS);                 // raw h3(s-1)
      if (s >= 1 && s < TT){
        #pragma unroll
        for (int e = 0; e < 4; ++e)
          hS[e] *= __expf(-fmaxf(dhC*WdhL[e] + bdhL[e], 0.f));
      }
      if (s < TT) fragW_lds(&sC[par][0], dG, r, hS);     // decayed h3 (B-operand)
      barrier_lds();
      if (s < TT){
        f16x8 bh4[4];
        #pragma unroll
        for (int kt = 0; kt < 4; ++kt) bh4[kt] = sC[par][kt*64 + lane];
        f32x4v Ci[3], Ch[3];
        #pragma unroll
        for (int g = 0; g < 3; ++g){ Ci[g] = (f32x4v){0,0,0,0}; Ch[g] = (f32x4v){0,0,0,0}; }
        #pragma unroll
        for (int g = 0; g < 3; ++g){
          #pragma unroll
          for (int kt = 0; kt < 4; ++kt) Ch[g] = MFMA(Ah[g][kt], bh4[kt], Ch[g]);
          #pragma unroll
          for (int kt = 0; kt < 4; ++kt) Ci[g] = MFMA(Ai[g][kt], bi[kt], Ci[g]);
        }
        if (s + 1 < TT){
          const char* sIn = ring1 + (size_t)((s+1) & (RING-1))*4096;
          #pragma unroll
          for (int kt = 0; kt < 4; ++kt) bi[kt] = impFrag(sIn, kt, lane);
        }
        gates_upd(Ci, Ch, bR, bZ, bI, bH, hS);
      }
      if (s >= 1 && wid == 4){
        f32x4v cl = {0.f,0.f,0.f,0.f};
        #pragma unroll
        for (int kt = 0; kt < 4; ++kt) cl = MFMA(aO[kt], sD[par][kt*64 + lane], cl);
        if (lane < 16){
          float l0 = cl[0]+bo4[0], l1 = cl[1]+bo4[1], l2 = cl[2]+bo4[2], l3 = cl[3]+bo4[3];
          float mx = fmaxf(fmaxf(l0,l1), fmaxf(l2,l3));
          float e0 = __expf(l0-mx), e1 = __expf(l1-mx), e2 = __expf(l2-mx), e3 = __expf(l3-mx);
          float inv = 1.f/(e0+e1+e2+e3);
          float4 o; o.x = e0*inv; o.y = e1*inv; o.z = e2*inv; o.w = e3*inv;
          *(float4*)(y + ((size_t)(b0+lane)*TT + (s-1))*4) = o;
        }
      }
      if ((s & 7) == 7 && s < TT){
        if (tid == 0) AT_ST32(ak1, (u32)(s+1));
        spin_ge(fl1, (u32)(s+17 <= TT ? s+17 : TT));
      }
      dhC = dhN;
      const int tp = (s+2 < TT) ? (s+2) : (TT-1);
      dhN = dd[(size_t)(b0+r)*TT + tp];
    }
  }
}

extern "C" void kernel_launch(void* const* d_in, const int* in_sizes, int n_in,
                              void* d_out, int out_size, void* d_ws, size_t ws_size,
                              hipStream_t stream) {
  (void)in_sizes; (void)n_in; (void)out_size; (void)ws_size;
  u32*  wsf = (u32*)d_ws;
  char* wsd = (char*)d_ws + 16384;
  k_init<<<dim3(16), dim3(256), 0, stream>>>(wsf);
  k_pipe<<<dim3(96), dim3(512), 0, stream>>>(
      (const float*)d_in[0],  (const float*)d_in[1],  (const float*)d_in[2],
      (const float*)d_in[3],  (const float*)d_in[4],  (const float*)d_in[5],
      (const float*)d_in[6],  (const float*)d_in[7],  (const float*)d_in[8],  (const float*)d_in[9],
      (const float*)d_in[10], (const float*)d_in[11], (const float*)d_in[12], (const float*)d_in[13],
      (const float*)d_in[14], (const float*)d_in[15], (const float*)d_in[16], (const float*)d_in[17],
      (const float*)d_in[18], (const float*)d_in[19],
      (const float*)d_in[20], (const float*)d_in[21],
      (const float*)d_in[22], (const float*)d_in[23],
      (float*)d_out, wsf, wsd);
}

// Round 4
// 1968.069 us; speedup vs baseline: 2.2716x; 1.0024x over previous
//
#include <hip/hip_runtime.h>

#define TT 512
#define VV 64
#define RING 16   // per channel; window 8, producer gate ACK >= t-8 (alias-safe by 1 slot)

typedef _Float16 f16;
typedef f16 f16x8 __attribute__((ext_vector_type(8)));
typedef f16 f16x4 __attribute__((ext_vector_type(4)));
typedef float f32x4v __attribute__((ext_vector_type(4)));
typedef unsigned long long u64;
typedef unsigned u32;

#define MFMA(A_,B_,C_) __builtin_amdgcn_mfma_f32_16x16x32_f16((A_),(B_),(C_),0,0,0)
#define AT_LD32(p)   __hip_atomic_load((p), __ATOMIC_RELAXED, __HIP_MEMORY_SCOPE_AGENT)
#define AT_ST32(p,v) __hip_atomic_store((p),(v), __ATOMIC_RELAXED, __HIP_MEMORY_SCOPE_AGENT)
#define AT_LD64(p)   __hip_atomic_load((p), __ATOMIC_RELAXED, __HIP_MEMORY_SCOPE_AGENT)
#define AT_ST64(p,v) __hip_atomic_store((p),(v), __ATOMIC_RELAXED, __HIP_MEMORY_SCOPE_AGENT)

__device__ __forceinline__ void barrier_lds(){ asm volatile("s_waitcnt lgkmcnt(0)\n\ts_barrier" ::: "memory"); }
__device__ __forceinline__ void wait_vm0(){ asm volatile("s_waitcnt vmcnt(0)" ::: "memory"); }
__device__ __forceinline__ float4 ld4(const float* p){ return *(const float4*)p; }

__device__ __forceinline__ f16x8 ldA8(const float* p){
  f16x8 a;
  #pragma unroll
  for (int j = 0; j < 8; ++j) a[j] = (f16)p[j];
  return a;
}

// element offset (in f16 units) of (k=d0..d0+3, col=b) inside a B-frag buffer
// layout: [kt][lane'][j], lane' = ((d&31)>>3)*16 + b, j = d&7
__device__ __forceinline__ int fragOff16(int d0, int b){
  const int kt = d0 >> 5, qq = (d0 >> 3) & 3, j0 = d0 & 7;
  return (kt*64 + qq*16 + b)*8 + j0;
}

__device__ __forceinline__ void fragW_lds(f16x8* buf, int d0, int b, const float* h4){
  f16x4 v;
  #pragma unroll
  for (int e = 0; e < 4; ++e) v[e] = (f16)h4[e];
  *(f16x4*)((f16*)buf + fragOff16(d0, b)) = v;
}

__device__ __forceinline__ void pubFrag(char* slot, int d0, int b, const float* h4){
  union { f16x4 v; u64 u; } uu;
  #pragma unroll
  for (int e = 0; e < 4; ++e) uu.v[e] = (f16)h4[e];
  AT_ST64((u64*)(slot + fragOff16(d0, b)*2), uu.u);
}

__device__ __forceinline__ f16x8 impFrag(const char* slot, int kt, int lane){
  union { u64 u[2]; f16x8 v; } vv;
  const u64* p = (const u64*)(slot + (kt*64 + lane)*16);
  vv.u[0] = AT_LD64((u64*)p);
  vv.u[1] = AT_LD64((u64*)(p + 1));
  return vv.v;
}

__device__ __forceinline__ void spin_ge(u32* f, u32 val){
  if ((threadIdx.x & 63) == 0){
    u32 g = 0;
    while (AT_LD32(f) < val && ++g < (1u << 20)) {}
  }
  asm volatile("" ::: "memory");
}

__device__ __forceinline__ void gates_upd(const f32x4v* Ci, const f32x4v* Ch,
                                          const float* bR, const float* bZ,
                                          const float* bI, const float* bH,
                                          float* hp){
  #pragma unroll
  for (int e = 0; e < 4; ++e){
    float rr = 1.f/(1.f + __expf(-(Ci[0][e] + Ch[0][e] + bR[e])));
    float zz = 1.f/(1.f + __expf(-(Ci[1][e] + Ch[1][e] + bZ[e])));
    float nv = Ci[2][e] + bI[e] + rr*(Ch[2][e] + bH[e]);
    float nn = 1.f - 2.f/(1.f + __expf(2.f*nv));
    hp[e] = (1.f - zz)*nn + zz*hp[e];
  }
}

__global__ void k_init(u32* wsf){
  const int i = blockIdx.x*256 + threadIdx.x;
  if (i < 4096) AT_ST32(wsf + i, 0u);
}

// blocks 0..31: L1 (x-path -> ch0); 32..63: L2 (ch0 -> ch1); 64..95: L3+head (ch1 -> y).
// All blocks: 512 threads = 8 waves, each wave owns ONE 16-row tile of H (G=1).
// REGISTER BUDGET (R2/R3 post-mortem): empirically hipcc's 2nd launch_bounds arg acts
// like CUDA minBlocksPerCU; (512,none)/(512,2) both budget 128 VGPR -> weight frags
// spill. amdgpu_waves_per_eu(2,2) pins exactly 2 waves/SIMD -> 256 VGPR/wave budget:
// role-1/2 working set (~210 VGPR) fits, and each SIMD gets 2 waves of TLP.
// Protocol per channel (verified R2/R3): flag = steps published, stored every 8 steps
// after vm0 drain + block barrier; consumer ACK = s+1 every 8 steps; producer gate at
// window start (t%8==0, t>=16): ACK >= t-8 (max written step = ACK+15; alias needs
// ACK+16 -> safe, incl. consumer's in-flight prefetch of slot ACK). Consumer window
// spin: flag >= min(s+17, TT). Initial consumer spin: flag >= 16.
__launch_bounds__(512)
__attribute__((amdgpu_waves_per_eu(2, 2)))
__global__ void k_pipe(const float* __restrict__ x,   const float* __restrict__ dd,
                       const float* __restrict__ m1,
                       const float* __restrict__ h01, const float* __restrict__ h02,
                       const float* __restrict__ h03,
                       const float* __restrict__ Wih1, const float* __restrict__ Whh1,
                       const float* __restrict__ bih1, const float* __restrict__ bhh1,
                       const float* __restrict__ Wih2, const float* __restrict__ Whh2,
                       const float* __restrict__ bih2, const float* __restrict__ bhh2,
                       const float* __restrict__ Wih3, const float* __restrict__ Whh3,
                       const float* __restrict__ bih3, const float* __restrict__ bhh3,
                       const float* __restrict__ Wout, const float* __restrict__ bout,
                       const float* __restrict__ Wdx,  const float* __restrict__ bdx,
                       const float* __restrict__ Wdh,  const float* __restrict__ bdh,
                       float* __restrict__ y, u32* __restrict__ wsf, char* __restrict__ wsd)
{
  __shared__ f16x8 sA[2][256];   // h staging (producer h1, L2 decayed-h2)
  __shared__ f16x8 sB[2][256];   // producer: x staging (first 128 used)
  __shared__ f16x8 sC[2][256];   // L3: decayed-h3 staging
  __shared__ f16x8 sD[2][256];   // L3: raw-h3 staging for delayed head

  const int tid = threadIdx.x, wid = tid >> 6, lane = tid & 63;
  const int q = lane >> 4, r = lane & 15;
  const int blk = blockIdx.x, role = blk >> 5, grp = blk & 31, b0 = grp << 4;

  u32* const FL  = wsf;
  u32* const ACK = wsf + 1024;
  u32* const fl0 = FL  + grp*16;
  u32* const ak0 = ACK + grp*16;
  u32* const fl1 = FL  + (32+grp)*16;
  u32* const ak1 = ACK + (32+grp)*16;
  char* const ring0 = wsd + (size_t)grp*RING*4096;
  char* const ring1 = wsd + (size_t)(32+grp)*RING*4096;

  const int dG = wid*16 + 4*q;

  const float* bihX = (role == 0) ? bih1 : (role == 1) ? bih2 : bih3;
  const float* bhhX = (role == 0) ? bhh1 : (role == 1) ? bhh2 : bhh3;
  const float* h0X  = (role == 0) ? h01  : (role == 1) ? h02  : h03;

  float bR[4], bZ[4], bI[4], bH[4], hS[4], WdhL[4], bdhL[4];
  #pragma unroll
  for (int e = 0; e < 4; ++e){
    const int d = dG + e;
    bR[e] = bihX[d] + bhhX[d];
    bZ[e] = bihX[128+d] + bhhX[128+d];
    bI[e] = bihX[256+d];
    bH[e] = bhhX[256+d];
    WdhL[e] = Wdh[d]; bdhL[e] = bdh[d];
  }
  { float4 a = ld4(h0X + (size_t)(b0+r)*128 + dG); hS[0]=a.x; hS[1]=a.y; hS[2]=a.z; hS[3]=a.w; }
  float dhC = 0.f, dhN = dd[(size_t)(b0+r)*TT + 1];

  // ===================== role 0: L1 producer =====================
  if (role == 0){
    f16x8 Ai[3][2], Ah[3][4];
    #pragma unroll
    for (int g = 0; g < 3; ++g){
      const int mrow = (g*8 + wid)*16 + r;
      #pragma unroll
      for (int kt = 0; kt < 2; ++kt) Ai[g][kt] = ldA8(Wih1 + mrow*64 + kt*32 + q*8);
      #pragma unroll
      for (int kt = 0; kt < 4; ++kt) Ah[g][kt] = ldA8(Whh1 + mrow*128 + kt*32 + q*8);
    }
    const int bx = (wid & 3)*4 + q, v0 = 4*r;
    float Wdx4[4] = {0,0,0,0}, bdx4[4] = {0,0,0,0};
    float4 xC = {0,0,0,0}, x0v = {0,0,0,0}, xN = {0,0,0,0}, mN = {0,0,0,0};
    float4 xP = {0,0,0,0}, mC = {0,0,0,0};
    float dxC = 0.f, dxN = 0.f;
    if (wid < 4){
      #pragma unroll
      for (int e = 0; e < 4; ++e){ Wdx4[e] = Wdx[v0+e]; bdx4[e] = bdx[v0+e]; }
      xC  = ld4(x + ((size_t)(b0+bx)*TT + 0)*VV + v0);
      x0v = xC;
      xN  = ld4(x  + ((size_t)(b0+bx)*TT + 1)*VV + v0);
      mN  = ld4(m1 + ((size_t)(b0+bx)*TT + 1)*VV + v0);
      dxN = dd[(size_t)(b0+bx)*TT + 1];
      xP = xC; mC = mN; dxC = dxN;
    }
    __syncthreads();

    for (int t = 0; t < TT; ++t){
      const int par = t & 1;
      if ((t & 7) == 0 && t >= 16) spin_ge(ak0, (u32)(t-8));
      if (wid < 4){
        float xi[4];
        if (t == 0){ xi[0]=xC.x; xi[1]=xC.y; xi[2]=xC.z; xi[3]=xC.w; }
        else {
          const float* xc = (const float*)&xC; const float* xp = (const float*)&xP;
          const float* x0e = (const float*)&x0v; const float* me = (const float*)&mC;
          #pragma unroll
          for (int e = 0; e < 4; ++e){
            float gx = __expf(-fmaxf(dxC*Wdx4[e] + bdx4[e], 0.f));
            xi[e] = (xp[e]*gx + (1.f-gx)*x0e[e])*(1.f-me[e]) + me[e]*xc[e];
          }
        }
        fragW_lds(&sB[par][0], v0, bx, xi);
      }
      if (t >= 1){
        #pragma unroll
        for (int e = 0; e < 4; ++e)
          hS[e] *= __expf(-fmaxf(dhC*WdhL[e] + bdhL[e], 0.f));
      }
      fragW_lds(&sA[par][0], dG, r, hS);
      barrier_lds();
      f16x8 bx1[2], bh4[4];
      #pragma unroll
      for (int kt = 0; kt < 2; ++kt) bx1[kt] = sB[par][kt*64 + lane];
      #pragma unroll
      for (int kt = 0; kt < 4; ++kt) bh4[kt] = sA[par][kt*64 + lane];
      f32x4v Ci[3], Ch[3];
      #pragma unroll
      for (int g = 0; g < 3; ++g){ Ci[g] = (f32x4v){0,0,0,0}; Ch[g] = (f32x4v){0,0,0,0}; }
      #pragma unroll
      for (int g = 0; g < 3; ++g){
        #pragma unroll
        for (int kt = 0; kt < 4; ++kt) Ch[g] = MFMA(Ah[g][kt], bh4[kt], Ch[g]);
        #pragma unroll
        for (int kt = 0; kt < 2; ++kt) Ci[g] = MFMA(Ai[g][kt], bx1[kt], Ci[g]);
      }
      gates_upd(Ci, Ch, bR, bZ, bI, bH, hS);
      pubFrag(ring0 + (size_t)(t & (RING-1))*4096, dG, r, hS);
      if ((t & 7) == 7){
        wait_vm0();
        barrier_lds();
        if (tid == 0) AT_ST32(fl0, (u32)(t+1));
      }
      dhC = dhN;
      const int tp = (t+2 < TT) ? (t+2) : (TT-1);
      dhN = dd[(size_t)(b0+r)*TT + tp];
      if (wid < 4){
        xP = xC; xC = xN; mC = mN; dxC = dxN;
        xN  = ld4(x  + ((size_t)(b0+bx)*TT + tp)*VV + v0);
        mN  = ld4(m1 + ((size_t)(b0+bx)*TT + tp)*VV + v0);
        dxN = dd[(size_t)(b0+bx)*TT + tp];
      }
    }
    return;
  }

  // ===================== role 1: L2 (ch0 -> ch1) =====================
  if (role == 1){
    f16x8 Ai[3][4], Ah[3][4];
    #pragma unroll
    for (int g = 0; g < 3; ++g){
      const int mrow = (g*8 + wid)*16 + r;
      #pragma unroll
      for (int kt = 0; kt < 4; ++kt){
        Ai[g][kt] = ldA8(Wih2 + mrow*128 + kt*32 + q*8);
        Ah[g][kt] = ldA8(Whh2 + mrow*128 + kt*32 + q*8);
      }
    }
    __syncthreads();

    spin_ge(fl0, 16u);
    f16x8 bi[4];
    #pragma unroll
    for (int kt = 0; kt < 4; ++kt) bi[kt] = impFrag(ring0, kt, lane);

    for (int s = 0; s < TT; ++s){
      const int par = s & 1;
      if ((s & 7) == 0 && s >= 16) spin_ge(ak1, (u32)(s-8));
      if (s >= 1){
        #pragma unroll
        for (int e = 0; e < 4; ++e)
          hS[e] *= __expf(-fmaxf(dhC*WdhL[e] + bdhL[e], 0.f));
      }
      fragW_lds(&sA[par][0], dG, r, hS);
      barrier_lds();
      f16x8 bh4[4];
      #pragma unroll
      for (int kt = 0; kt < 4; ++kt) bh4[kt] = sA[par][kt*64 + lane];
      f32x4v Ci[3], Ch[3];
      #pragma unroll
      for (int g = 0; g < 3; ++g){ Ci[g] = (f32x4v){0,0,0,0}; Ch[g] = (f32x4v){0,0,0,0}; }
      #pragma unroll
      for (int g = 0; g < 3; ++g){
        #pragma unroll
        for (int kt = 0; kt < 4; ++kt) Ch[g] = MFMA(Ah[g][kt], bh4[kt], Ch[g]);
        #pragma unroll
        for (int kt = 0; kt < 4; ++kt) Ci[g] = MFMA(Ai[g][kt], bi[kt], Ci[g]);
      }
      if (s + 1 < TT){
        const char* sIn = ring0 + (size_t)((s+1) & (RING-1))*4096;
        #pragma unroll
        for (int kt = 0; kt < 4; ++kt) bi[kt] = impFrag(sIn, kt, lane);
      }
      gates_upd(Ci, Ch, bR, bZ, bI, bH, hS);
      pubFrag(ring1 + (size_t)(s & (RING-1))*4096, dG, r, hS);
      if ((s & 7) == 7){
        wait_vm0();
        barrier_lds();
        if (tid == 0){ AT_ST32(fl1, (u32)(s+1)); AT_ST32(ak0, (u32)(s+1)); }
        spin_ge(fl0, (u32)(s+17 <= TT ? s+17 : TT));
      }
      dhC = dhN;
      const int tp = (s+2 < TT) ? (s+2) : (TT-1);
      dhN = dd[(size_t)(b0+r)*TT + tp];
    }
    return;
  }

  // ===================== role 2: L3 + head (ch1 -> y) =====================
  {
    f16x8 Ai[3][4], Ah[3][4];
    #pragma unroll
    for (int g = 0; g < 3; ++g){
      const int mrow = (g*8 + wid)*16 + r;
      #pragma unroll
      for (int kt = 0; kt < 4; ++kt){
        Ai[g][kt] = ldA8(Wih3 + mrow*128 + kt*32 + q*8);
        Ah[g][kt] = ldA8(Whh3 + mrow*128 + kt*32 + q*8);
      }
    }
    f16x8 aO[4]; float bo4[4] = {0,0,0,0};
    if (wid == 4){
      #pragma unroll
      for (int kt = 0; kt < 4; ++kt){
        f16x8 a;
        #pragma unroll
        for (int j = 0; j < 8; ++j)
          a[j] = (r < 4) ? (f16)Wout[r*128 + kt*32 + q*8 + j] : (f16)0.f;
        aO[kt] = a;
      }
      #pragma unroll
      for (int e = 0; e < 4; ++e) bo4[e] = bout[e];
    }
    __syncthreads();

    spin_ge(fl1, 16u);
    f16x8 bi[4];
    #pragma unroll
    for (int kt = 0; kt < 4; ++kt) bi[kt] = impFrag(ring1, kt, lane);

    // s in [0, TT]: GRU step s for s<TT; head(h3(s-1)) -> y(s-1) for s>=1 (delayed head, one barrier)
    for (int s = 0; s <= TT; ++s){
      const int par = s & 1;
      fragW_lds(&sD[par][0], dG, r, hS);                 // raw h3(s-1)
      if (s >= 1 && s < TT){
        #pragma unroll
        for (int e = 0; e < 4; ++e)
          hS[e] *= __expf(-fmaxf(dhC*WdhL[e] + bdhL[e], 0.f));
      }
      if (s < TT) fragW_lds(&sC[par][0], dG, r, hS);     // decayed h3 (B-operand)
      barrier_lds();
      if (s < TT){
        f16x8 bh4[4];
        #pragma unroll
        for (int kt = 0; kt < 4; ++kt) bh4[kt] = sC[par][kt*64 + lane];
        f32x4v Ci[3], Ch[3];
        #pragma unroll
        for (int g = 0; g < 3; ++g){ Ci[g] = (f32x4v){0,0,0,0}; Ch[g] = (f32x4v){0,0,0,0}; }
        #pragma unroll
        for (int g = 0; g < 3; ++g){
          #pragma unroll
          for (int kt = 0; kt < 4; ++kt) Ch[g] = MFMA(Ah[g][kt], bh4[kt], Ch[g]);
          #pragma unroll
          for (int kt = 0; kt < 4; ++kt) Ci[g] = MFMA(Ai[g][kt], bi[kt], Ci[g]);
        }
        if (s + 1 < TT){
          const char* sIn = ring1 + (size_t)((s+1) & (RING-1))*4096;
          #pragma unroll
          for (int kt = 0; kt < 4; ++kt) bi[kt] = impFrag(sIn, kt, lane);
        }
        gates_upd(Ci, Ch, bR, bZ, bI, bH, hS);
      }
      if (s >= 1 && wid == 4){
        f32x4v cl = {0.f,0.f,0.f,0.f};
        #pragma unroll
        for (int kt = 0; kt < 4; ++kt) cl = MFMA(aO[kt], sD[par][kt*64 + lane], cl);
        if (lane < 16){
          float l0 = cl[0]+bo4[0], l1 = cl[1]+bo4[1], l2 = cl[2]+bo4[2], l3 = cl[3]+bo4[3];
          float mx = fmaxf(fmaxf(l0,l1), fmaxf(l2,l3));
          float e0 = __expf(l0-mx), e1 = __expf(l1-mx), e2 = __expf(l2-mx), e3 = __expf(l3-mx);
          float inv = 1.f/(e0+e1+e2+e3);
          float4 o; o.x = e0*inv; o.y = e1*inv; o.z = e2*inv; o.w = e3*inv;
          *(float4*)(y + ((size_t)(b0+lane)*TT + (s-1))*4) = o;
        }
      }
      if ((s & 7) == 7 && s < TT){
        if (tid == 0) AT_ST32(ak1, (u32)(s+1));
        spin_ge(fl1, (u32)(s+17 <= TT ? s+17 : TT));
      }
      dhC = dhN;
      const int tp = (s+2 < TT) ? (s+2) : (TT-1);
      dhN = dd[(size_t)(b0+r)*TT + tp];
    }
  }
}

extern "C" void kernel_launch(void* const* d_in, const int* in_sizes, int n_in,
                              void* d_out, int out_size, void* d_ws, size_t ws_size,
                              hipStream_t stream) {
  (void)in_sizes; (void)n_in; (void)out_size; (void)ws_size;
  u32*  wsf = (u32*)d_ws;
  char* wsd = (char*)d_ws + 16384;
  k_init<<<dim3(16), dim3(256), 0, stream>>>(wsf);
  k_pipe<<<dim3(96), dim3(512), 0, stream>>>(
      (const float*)d_in[0],  (const float*)d_in[1],  (const float*)d_in[2],
      (const float*)d_in[3],  (const float*)d_in[4],  (const float*)d_in[5],
      (const float*)d_in[6],  (const float*)d_in[7],  (const float*)d_in[8],  (const float*)d_in[9],
      (const float*)d_in[10], (const float*)d_in[11], (const float*)d_in[12], (const float*)d_in[13],
      (const float*)d_in[14], (const float*)d_in[15], (const float*)d_in[16], (const float*)d_in[17],
      (const float*)d_in[18], (const float*)d_in[19],
      (const float*)d_in[20], (const float*)d_in[21],
      (const float*)d_in[22], (const float*)d_in[23],
      (float*)d_out, wsf, wsd);
}

// Round 5
// 1428.455 us; speedup vs baseline: 3.1297x; 1.3778x over previous
//
#include <hip/hip_runtime.h>

#define TT 512
#define VV 64
#define RING 16   // 16 slots/channel; window-4 flag quantum, per-step ACKs (R1-measured protocol)

typedef _Float16 f16;
typedef f16 f16x8 __attribute__((ext_vector_type(8)));
typedef f16 f16x4 __attribute__((ext_vector_type(4)));
typedef float f32x4v __attribute__((ext_vector_type(4)));
typedef unsigned long long u64;
typedef unsigned u32;

#define MFMA(A_,B_,C_) __builtin_amdgcn_mfma_f32_16x16x32_f16((A_),(B_),(C_),0,0,0)
#define AT_LD32(p)   __hip_atomic_load((p), __ATOMIC_RELAXED, __HIP_MEMORY_SCOPE_AGENT)
#define AT_ST32(p,v) __hip_atomic_store((p),(v), __ATOMIC_RELAXED, __HIP_MEMORY_SCOPE_AGENT)
#define AT_LD64(p)   __hip_atomic_load((p), __ATOMIC_RELAXED, __HIP_MEMORY_SCOPE_AGENT)
#define AT_ST64(p,v) __hip_atomic_store((p),(v), __ATOMIC_RELAXED, __HIP_MEMORY_SCOPE_AGENT)

__device__ __forceinline__ void barrier_lds(){ asm volatile("s_waitcnt lgkmcnt(0)\n\ts_barrier" ::: "memory"); }
__device__ __forceinline__ void wait_vm0(){ asm volatile("s_waitcnt vmcnt(0)" ::: "memory"); }
__device__ __forceinline__ float4 ld4(const float* p){ return *(const float4*)p; }

__device__ __forceinline__ f16x8 ldA8(const float* p){
  f16x8 a;
  #pragma unroll
  for (int j = 0; j < 8; ++j) a[j] = (f16)p[j];
  return a;
}

// element offset (in f16 units) of (k=d0..d0+3, col=b) inside a B-frag buffer
// layout: [kt][lane'][j], lane' = ((d&31)>>3)*16 + b, j = d&7
__device__ __forceinline__ int fragOff16(int d0, int b){
  const int kt = d0 >> 5, qq = (d0 >> 3) & 3, j0 = d0 & 7;
  return (kt*64 + qq*16 + b)*8 + j0;
}

__device__ __forceinline__ void fragW_lds(f16x8* buf, int d0, int b, const float* h4){
  f16x4 v;
  #pragma unroll
  for (int e = 0; e < 4; ++e) v[e] = (f16)h4[e];
  *(f16x4*)((f16*)buf + fragOff16(d0, b)) = v;
}

__device__ __forceinline__ void pubFrag(char* slot, int d0, int b, const float* h4){
  union { f16x4 v; u64 u; } uu;
  #pragma unroll
  for (int e = 0; e < 4; ++e) uu.v[e] = (f16)h4[e];
  AT_ST64((u64*)(slot + fragOff16(d0, b)*2), uu.u);
}

__device__ __forceinline__ f16x8 impFrag(const char* slot, int kt, int lane){
  union { u64 u[2]; f16x8 v; } vv;
  const u64* p = (const u64*)(slot + (kt*64 + lane)*16);
  vv.u[0] = AT_LD64((u64*)p);
  vv.u[1] = AT_LD64((u64*)(p + 1));
  return vv.v;
}

__device__ __forceinline__ void spin_ge(u32* f, u32 val){
  if ((threadIdx.x & 63) == 0){
    u32 g = 0;
    while (AT_LD32(f) < val && ++g < (1u << 20)) {}
  }
  asm volatile("" ::: "memory");
}

__device__ __forceinline__ void gates_upd(const f32x4v* Ci, const f32x4v* Ch,
                                          const float* bR, const float* bZ,
                                          const float* bI, const float* bH,
                                          float* hp){
  #pragma unroll
  for (int e = 0; e < 4; ++e){
    float rr = 1.f/(1.f + __expf(-(Ci[0][e] + Ch[0][e] + bR[e])));
    float zz = 1.f/(1.f + __expf(-(Ci[1][e] + Ch[1][e] + bZ[e])));
    float nv = Ci[2][e] + bI[e] + rr*(Ch[2][e] + bH[e]);
    float nn = 1.f - 2.f/(1.f + __expf(2.f*nv));
    hp[e] = (1.f - zz)*nn + zz*hp[e];
  }
}

__global__ void k_init(u32* wsf){
  const int i = blockIdx.x*256 + threadIdx.x;
  if (i < 4096) AT_ST32(wsf + i, 0u);
}

// roles: 0=L1 (x-path -> ch0), 1=L2 (ch0->ch1), 2=L3+head (ch1 -> y)
// REGISTER BUDGET (R2-R4 post-mortems): role-1/2 live set ~330 VGPR (192 weight frags
// + acc/bias/import). R0/R1 compiled at the 256 boundary (2 waves/EU target) ->
// ~60-80 VGPR spilled/remat'd INSIDE the 512-step serial loop = the dominant
// unexplained stall. waves_per_eu(1,1) pins 1 wave/EU -> full 512-VGPR budget,
// making the working set resident. Occupancy was ~1.5 waves/CU anyway - nothing lost.
// Protocol: R1-measured (window-4 flag+vm0 drain, per-step ACKs, RING 16, prefetch-1).
__launch_bounds__(256)
__attribute__((amdgpu_waves_per_eu(1, 1)))
__global__ void k_pipe(const float* __restrict__ x,   const float* __restrict__ dd,
                       const float* __restrict__ m1,
                       const float* __restrict__ h01, const float* __restrict__ h02,
                       const float* __restrict__ h03,
                       const float* __restrict__ Wih1, const float* __restrict__ Whh1,
                       const float* __restrict__ bih1, const float* __restrict__ bhh1,
                       const float* __restrict__ Wih2, const float* __restrict__ Whh2,
                       const float* __restrict__ bih2, const float* __restrict__ bhh2,
                       const float* __restrict__ Wih3, const float* __restrict__ Whh3,
                       const float* __restrict__ bih3, const float* __restrict__ bhh3,
                       const float* __restrict__ Wout, const float* __restrict__ bout,
                       const float* __restrict__ Wdx,  const float* __restrict__ bdx,
                       const float* __restrict__ Wdh,  const float* __restrict__ bdh,
                       float* __restrict__ y, u32* __restrict__ wsf, char* __restrict__ wsd)
{
  __shared__ f16x8 sFrag[2][256];
  __shared__ f16x8 sX1[2][128];
  __shared__ f16x8 sHead[2][256];

  const int tid = threadIdx.x, w = tid >> 6, lane = tid & 63;
  const int q = lane >> 4, r = lane & 15;
  const int blk = blockIdx.x, role = blk >> 5, grp = blk & 31, b0 = grp << 4;

  u32* const FL  = wsf;
  u32* const ACK = wsf + 1024;

#define SLOT(ch,s) (wsd + (size_t)((((ch)*32 + grp)*RING + (s)))*4096)
#define FLP(ch)    (FL  + ((ch)*32 + grp)*16)
#define ACKP(ch)   (ACK + ((ch)*32 + grp)*16)

  // ---- per-thread hidden-dim biases (all roles L1..L3) ----
  const float* bihX = (role == 0) ? bih1 : (role == 1) ? bih2 : bih3;
  const float* bhhX = (role == 0) ? bhh1 : (role == 1) ? bhh2 : bhh3;
  const float* h0X  = (role == 0) ? h01  : (role == 1) ? h02  : h03;

  float bR[2][4], bZ[2][4], bI[2][4], bH[2][4];
  float hS[2][4], WdhL[2][4], bdhL[2][4];
  #pragma unroll
  for (int G = 0; G < 2; ++G){
    const int dG = (w + 4*G)*16 + 4*q;
    #pragma unroll
    for (int e = 0; e < 4; ++e){
      const int d = dG + e;
      bR[G][e] = bihX[d] + bhhX[d];
      bZ[G][e] = bihX[128+d] + bhhX[128+d];
      bI[G][e] = bihX[256+d];
      bH[G][e] = bhhX[256+d];
      WdhL[G][e] = Wdh[d]; bdhL[G][e] = bdh[d];
    }
    float4 a = ld4(h0X + (size_t)(b0+r)*128 + dG);
    hS[G][0]=a.x; hS[G][1]=a.y; hS[G][2]=a.z; hS[G][3]=a.w;
  }
  float dhC = 0.f, dhN = dd[(size_t)(b0+r)*TT + 1];

  // ===================== L1 =====================
  if (role == 0){
    f16x8 Ai[2][3][2], Ah[2][3][4];
    #pragma unroll
    for (int G = 0; G < 2; ++G){
      #pragma unroll
      for (int g = 0; g < 3; ++g){
        const int mrow = (g*8 + w + 4*G)*16 + r;
        #pragma unroll
        for (int kt = 0; kt < 2; ++kt) Ai[G][g][kt] = ldA8(Wih1 + mrow*64 + kt*32 + q*8);
        #pragma unroll
        for (int kt = 0; kt < 4; ++kt) Ah[G][g][kt] = ldA8(Whh1 + mrow*128 + kt*32 + q*8);
      }
    }
    const int bx = w*4 + q, v0 = 4*r;
    float Wdx4[4], bdx4[4];
    #pragma unroll
    for (int e = 0; e < 4; ++e){ Wdx4[e] = Wdx[v0+e]; bdx4[e] = bdx[v0+e]; }

    float4 xC = ld4(x + ((size_t)(b0+bx)*TT + 0)*VV + v0);
    const float4 x0v = xC;
    float4 xN = ld4(x  + ((size_t)(b0+bx)*TT + 1)*VV + v0);
    float4 mN = ld4(m1 + ((size_t)(b0+bx)*TT + 1)*VV + v0);
    float dxN = dd[(size_t)(b0+bx)*TT + 1];
    float4 xP = xC, mC = mN; float dxC = dxN;
    __syncthreads();

    for (int t = 0; t < TT; ++t){
      const int par = t & 1;
      if ((t & 3) == 0 && t >= 16) spin_ge(ACKP(0), (u32)(t-13));
      float xi[4];
      if (t == 0){ xi[0]=xC.x; xi[1]=xC.y; xi[2]=xC.z; xi[3]=xC.w; }
      else {
        const float* xc = (const float*)&xC; const float* xp = (const float*)&xP;
        const float* x0e = (const float*)&x0v; const float* me = (const float*)&mC;
        #pragma unroll
        for (int e = 0; e < 4; ++e){
          float gx = __expf(-fmaxf(dxC*Wdx4[e] + bdx4[e], 0.f));
          xi[e] = (xp[e]*gx + (1.f-gx)*x0e[e])*(1.f-me[e]) + me[e]*xc[e];
        }
      }
      fragW_lds(&sX1[par][0], v0, bx, xi);
      #pragma unroll
      for (int G = 0; G < 2; ++G){
        const int dG = (w + 4*G)*16 + 4*q;
        if (t >= 1){
          #pragma unroll
          for (int e = 0; e < 4; ++e)
            hS[G][e] *= __expf(-fmaxf(dhC*WdhL[G][e] + bdhL[G][e], 0.f));
        }
        fragW_lds(&sFrag[par][0], dG, r, hS[G]);
      }
      barrier_lds();
      f16x8 bx1[2], bh4[4];
      #pragma unroll
      for (int kt = 0; kt < 2; ++kt) bx1[kt] = sX1[par][kt*64 + lane];
      #pragma unroll
      for (int kt = 0; kt < 4; ++kt) bh4[kt] = sFrag[par][kt*64 + lane];
      f32x4v Ci[2][3], Ch[2][3];
      #pragma unroll
      for (int G = 0; G < 2; ++G)
        #pragma unroll
        for (int g = 0; g < 3; ++g){ Ci[G][g] = (f32x4v){0,0,0,0}; Ch[G][g] = (f32x4v){0,0,0,0}; }
      #pragma unroll
      for (int G = 0; G < 2; ++G)
        #pragma unroll
        for (int g = 0; g < 3; ++g){
          #pragma unroll
          for (int kt = 0; kt < 4; ++kt) Ch[G][g] = MFMA(Ah[G][g][kt], bh4[kt], Ch[G][g]);
          #pragma unroll
          for (int kt = 0; kt < 2; ++kt) Ci[G][g] = MFMA(Ai[G][g][kt], bx1[kt], Ci[G][g]);
        }
      char* sOut = SLOT(0, t & (RING-1));
      #pragma unroll
      for (int G = 0; G < 2; ++G){
        const int dG = (w + 4*G)*16 + 4*q;
        gates_upd(&Ci[G][0], &Ch[G][0], bR[G], bZ[G], bI[G], bH[G], hS[G]);
        pubFrag(sOut, dG, r, hS[G]);
      }
      if ((t & 3) == 3){
        wait_vm0();
        barrier_lds();
        if (tid == 0) AT_ST32(FLP(0), (u32)(t+1));
      }
      xP = xC; xC = xN; mC = mN; dhC = dhN; dxC = dxN;
      const int tp = (t+2 < TT) ? (t+2) : (TT-1);
      xN  = ld4(x  + ((size_t)(b0+bx)*TT + tp)*VV + v0);
      mN  = ld4(m1 + ((size_t)(b0+bx)*TT + tp)*VV + v0);
      dhN = dd[(size_t)(b0+r)*TT + tp];
      dxN = dd[(size_t)(b0+bx)*TT + tp];
    }
    return;
  }

  // ===================== L2 / L3+head =====================
  {
    const float* Wihp = (role == 1) ? Wih2 : Wih3;
    const float* Whhp = (role == 1) ? Whh2 : Whh3;
    const int cIn = role - 1;

    f16x8 Ai[2][3][4], Ah[2][3][4];
    #pragma unroll
    for (int G = 0; G < 2; ++G){
      #pragma unroll
      for (int g = 0; g < 3; ++g){
        const int mrow = (g*8 + w + 4*G)*16 + r;
        #pragma unroll
        for (int kt = 0; kt < 4; ++kt){
          Ai[G][g][kt] = ldA8(Wihp + mrow*128 + kt*32 + q*8);
          Ah[G][g][kt] = ldA8(Whhp + mrow*128 + kt*32 + q*8);
        }
      }
    }
    // head weights (role 2 only; all waves compute, wave0 stores)
    f16x8 aO[4]; float bo4[4];
    if (role == 2){
      #pragma unroll
      for (int kt = 0; kt < 4; ++kt){
        f16x8 a;
        #pragma unroll
        for (int j = 0; j < 8; ++j)
          a[j] = (r < 4) ? (f16)Wout[r*128 + kt*32 + q*8 + j] : (f16)0.f;
        aO[kt] = a;
      }
      #pragma unroll
      for (int e = 0; e < 4; ++e) bo4[e] = bout[e];
    }
    __syncthreads();

    // preload: wait for first 8 steps (covers prefetch of slots 1..7 in window 0),
    // import step 0
    spin_ge(FLP(cIn), 8u);
    f16x8 bi[4], biN[4];
    #pragma unroll
    for (int kt = 0; kt < 4; ++kt) bi[kt] = impFrag(SLOT(cIn, 0), kt, lane);

    for (int t = 0; t < TT; ++t){
      const int par = t & 1;
      if (role == 1 && (t & 3) == 0 && t >= 16) spin_ge(ACKP(1), (u32)(t-13));
      // prefetch NEXT step's input frags at START of step t: a full step of compute
      // covers the L3-class import latency. Validity: slots <= FLP-1, and the window
      // spins (target t+7) keep slot t+1 always granted.
      if (t + 1 < TT){
        const char* sIn = SLOT(cIn, (t+1) & (RING-1));
        #pragma unroll
        for (int kt = 0; kt < 4; ++kt) biN[kt] = impFrag(sIn, kt, lane);
      }
      #pragma unroll
      for (int G = 0; G < 2; ++G){
        const int dG = (w + 4*G)*16 + 4*q;
        if (t >= 1){
          #pragma unroll
          for (int e = 0; e < 4; ++e)
            hS[G][e] *= __expf(-fmaxf(dhC*WdhL[G][e] + bdhL[G][e], 0.f));
        }
        fragW_lds(&sFrag[par][0], dG, r, hS[G]);
      }
      barrier_lds();
      if (role == 1 && tid == 0) AT_ST32(ACKP(0), (u32)t);   // steps <= t-1 fully consumed
      f16x8 bh4[4];
      #pragma unroll
      for (int kt = 0; kt < 4; ++kt) bh4[kt] = sFrag[par][kt*64 + lane];
      f32x4v Ci[2][3], Ch[2][3];
      #pragma unroll
      for (int G = 0; G < 2; ++G)
        #pragma unroll
        for (int g = 0; g < 3; ++g){ Ci[G][g] = (f32x4v){0,0,0,0}; Ch[G][g] = (f32x4v){0,0,0,0}; }
      #pragma unroll
      for (int G = 0; G < 2; ++G)
        #pragma unroll
        for (int g = 0; g < 3; ++g){
          #pragma unroll
          for (int kt = 0; kt < 4; ++kt) Ch[G][g] = MFMA(Ah[G][g][kt], bh4[kt], Ch[G][g]);
          #pragma unroll
          for (int kt = 0; kt < 4; ++kt) Ci[G][g] = MFMA(Ai[G][g][kt], bi[kt], Ci[G][g]);
        }
      #pragma unroll
      for (int G = 0; G < 2; ++G)
        gates_upd(&Ci[G][0], &Ch[G][0], bR[G], bZ[G], bI[G], bH[G], hS[G]);

      if (role == 1){
        char* sOut = SLOT(1, t & (RING-1));
        #pragma unroll
        for (int G = 0; G < 2; ++G){
          const int dG = (w + 4*G)*16 + 4*q;
          pubFrag(sOut, dG, r, hS[G]);
        }
        if ((t & 3) == 3){
          wait_vm0();
          barrier_lds();
          if (tid == 0) AT_ST32(FLP(1), (u32)(t+1));
          if (t < TT-1) spin_ge(FLP(0), (u32)(t+7 <= TT ? t+7 : TT));
        }
      } else {
        // head: write fresh h3 frags, barrier, MFMA + softmax, store y[., t, .]
        #pragma unroll
        for (int G = 0; G < 2; ++G){
          const int dG = (w + 4*G)*16 + 4*q;
          fragW_lds(&sHead[par][0], dG, r, hS[G]);
        }
        barrier_lds();
        if (tid == 0) AT_ST32(ACKP(1), (u32)(t+1));   // step t consumed
        f32x4v cl = {0.f,0.f,0.f,0.f};
        #pragma unroll
        for (int kt = 0; kt < 4; ++kt) cl = MFMA(aO[kt], sHead[par][kt*64 + lane], cl);
        if (tid < 16){
          float l0 = cl[0]+bo4[0], l1 = cl[1]+bo4[1], l2 = cl[2]+bo4[2], l3 = cl[3]+bo4[3];
          float mx = fmaxf(fmaxf(l0,l1), fmaxf(l2,l3));
          float e0 = __expf(l0-mx), e1 = __expf(l1-mx), e2 = __expf(l2-mx), e3 = __expf(l3-mx);
          float inv = 1.f/(e0+e1+e2+e3);
          float4 o; o.x = e0*inv; o.y = e1*inv; o.z = e2*inv; o.w = e3*inv;
          *(float4*)(y + ((size_t)(b0+tid)*TT + t)*4) = o;
        }
        if ((t & 3) == 3 && t < TT-1) spin_ge(FLP(1), (u32)(t+7 <= TT ? t+7 : TT));
      }

      // rotate prefetch buffer into place
      if (t + 1 < TT){
        #pragma unroll
        for (int kt = 0; kt < 4; ++kt) bi[kt] = biN[kt];
      }
      dhC = dhN;
      const int tp = (t+2 < TT) ? (t+2) : (TT-1);
      dhN = dd[(size_t)(b0+r)*TT + tp];
    }
  }
}

extern "C" void kernel_launch(void* const* d_in, const int* in_sizes, int n_in,
                              void* d_out, int out_size, void* d_ws, size_t ws_size,
                              hipStream_t stream) {
  (void)in_sizes; (void)n_in; (void)out_size; (void)ws_size;
  u32*  wsf = (u32*)d_ws;
  char* wsd = (char*)d_ws + 16384;
  k_init<<<dim3(16), dim3(256), 0, stream>>>(wsf);
  k_pipe<<<dim3(96), dim3(256), 0, stream>>>(
      (const float*)d_in[0],  (const float*)d_in[1],  (const float*)d_in[2],
      (const float*)d_in[3],  (const float*)d_in[4],  (const float*)d_in[5],
      (const float*)d_in[6],  (const float*)d_in[7],  (const float*)d_in[8],  (const float*)d_in[9],
      (const float*)d_in[10], (const float*)d_in[11], (const float*)d_in[12], (const float*)d_in[13],
      (const float*)d_in[14], (const float*)d_in[15], (const float*)d_in[16], (const float*)d_in[17],
      (const float*)d_in[18], (const float*)d_in[19],
      (const float*)d_in[20], (const float*)d_in[21],
      (const float*)d_in[22], (const float*)d_in[23],
      (float*)d_out, wsf, wsd);
}